// Round 5
// baseline (234.240 us; speedup 1.0000x reference)
//
#include <hip/hip_runtime.h>

#define N_NODES 50000
#define N_EDGES 800000
#define IN_CH 128
#define HID_CH 256
#define OUT_CH 128

constexpr int TOTAL_E = N_EDGES + N_NODES;      // edges + self loops = 850000
constexpr int FILL_BLOCKS = 256;
constexpr int EPB = N_EDGES / FILL_BLOCKS;      // 3125 (exact)
constexpr int TOT9 = N_NODES * 9;               // 9 slots/node: 8 groups + selfloop
constexpr int SCAN_BLK = 1024;
constexpr int NB9 = (TOT9 + SCAN_BLK - 1) / SCAN_BLK;  // 440

typedef __attribute__((ext_vector_type(8))) short bf16x8;
typedef __attribute__((ext_vector_type(4))) float f32x4;
typedef __attribute__((ext_vector_type(4))) unsigned int u32x4;

// ---------------- bf16 helpers ----------------

__device__ __forceinline__ unsigned int bf16rn(float x) {
    unsigned int u = __float_as_uint(x);
    return (u + 0x7fffu + ((u >> 16) & 1u)) >> 16;   // round-to-nearest-even
}

__device__ __forceinline__ void split2(float x0, float x1,
                                       unsigned int& h, unsigned int& l) {
    unsigned int h0 = bf16rn(x0), h1 = bf16rn(x1);
    float f0 = __uint_as_float(h0 << 16), f1 = __uint_as_float(h1 << 16);
    unsigned int l0 = bf16rn(x0 - f0), l1 = bf16rn(x1 - f1);
    h = h0 | (h1 << 16);
    l = l0 | (l1 << 16);
}

__device__ __forceinline__ bf16x8 asbf(u32x4 v) {
    return __builtin_bit_cast(bf16x8, v);
}

// ---------------- fp32 -> bf16 row copy ----------------

__global__ void k_tobf(const float* __restrict__ x, unsigned short* __restrict__ xb,
                       int n8) {
    int i = blockIdx.x * blockDim.x + threadIdx.x;
    if (i >= n8) return;
    const float4* p = (const float4*)(x + (size_t)i * 8);
    float4 a = p[0], b = p[1];
    u32x4 w;
    w.x = bf16rn(a.x) | (bf16rn(a.y) << 16);
    w.y = bf16rn(a.z) | (bf16rn(a.w) << 16);
    w.z = bf16rn(b.x) | (bf16rn(b.y) << 16);
    w.w = bf16rn(b.z) | (bf16rn(b.w) << 16);
    *(u32x4*)(xb + (size_t)i * 8) = w;
}

// ---------------- CSR construction (group-partitioned, col-only) ----------------
// Per-node layout: 9 contiguous sub-segments [g=0..7 edge groups, g=8 self loop].
// Edge e belongs to chunk e/EPB; chunk c is processed by fill-block b=c with
// group g = b&7 -> all writers of one (v,g) sub-segment run on one XCD
// (empirical blockIdx%8 round-robin), killing cross-XCD partial-line evictions.

__global__ void k_init9(int* __restrict__ deg9, int* __restrict__ cur9) {
    int i = blockIdx.x * blockDim.x + threadIdx.x;
    if (i < TOT9) { deg9[i] = (i % 9 == 8) ? 1 : 0; cur9[i] = 0; }
}

__global__ void k_hist9(const int* __restrict__ dst, int* __restrict__ deg9) {
    int e = blockIdx.x * blockDim.x + threadIdx.x;
    if (e < N_EDGES) {
        int g = (e / EPB) & 7;
        atomicAdd(&deg9[dst[e] * 9 + g], 1);
    }
}

__global__ void k_scan1(const int* __restrict__ cnt, int* __restrict__ incl,
                        int* __restrict__ part, int n) {
    __shared__ int s[SCAN_BLK];
    int t = threadIdx.x;
    int i = blockIdx.x * SCAN_BLK + t;
    int v = (i < n) ? cnt[i] : 0;
    s[t] = v; __syncthreads();
    for (int o = 1; o < SCAN_BLK; o <<= 1) {
        int a = (t >= o) ? s[t - o] : 0;
        __syncthreads();
        s[t] += a;
        __syncthreads();
    }
    if (i < n) incl[i] = s[t];
    if (t == SCAN_BLK - 1) part[blockIdx.x] = s[t];
}

__global__ void k_scan2(int* __restrict__ part) {   // scans NB9 partials, 1 block
    __shared__ int s[SCAN_BLK];
    int t = threadIdx.x;
    int v = (t < NB9) ? part[t] : 0;
    s[t] = v; __syncthreads();
    for (int o = 1; o < SCAN_BLK; o <<= 1) {
        int a = (t >= o) ? s[t - o] : 0;
        __syncthreads();
        s[t] += a;
        __syncthreads();
    }
    if (t < NB9) part[t] = s[t] - v;    // exclusive
}

// off9[i] = exclusive scan of deg9; written in place over incl
__global__ void k_off9(int* __restrict__ incl, const int* __restrict__ deg9,
                       const int* __restrict__ part) {
    int i = blockIdx.x * blockDim.x + threadIdx.x;
    if (i < TOT9) incl[i] = part[i >> 10] + incl[i] - deg9[i];
}

// per-node start/len/dis
__global__ void k_post(const int* __restrict__ off9, int* __restrict__ off,
                       int* __restrict__ len, float* __restrict__ dis) {
    int v = blockIdx.x * blockDim.x + threadIdx.x;
    if (v < N_NODES) {
        int s  = off9[v * 9];
        int nx = (v == N_NODES - 1) ? TOTAL_E : off9[v * 9 + 9];
        int l  = nx - s;
        off[v] = s; len[v] = l;
        dis[v] = rsqrtf((float)l);      // l >= 1 always
    }
}

__global__ __launch_bounds__(256)
void k_fill9(const int* __restrict__ src, const int* __restrict__ dst,
             const int* __restrict__ off9, int* __restrict__ cur9,
             int* __restrict__ col) {
    int b = blockIdx.x;                 // chunk id == block id (256 blocks)
    int g = b & 7;
    int e0 = b * EPB;
    for (int i = threadIdx.x; i < EPB; i += 256) {
        int e = e0 + i;
        int d = dst[e];
        int pos = off9[d * 9 + g] + atomicAdd(&cur9[d * 9 + g], 1);
        col[pos] = src[e];
    }
}

__global__ void k_fillself(const int* __restrict__ off9, int* __restrict__ col) {
    int v = blockIdx.x * blockDim.x + threadIdx.x;
    if (v < N_NODES) col[off9[v * 9 + 8]] = v;
}

// ---- bf16 aggregation: out[v] = sum_e dis[c_e]*dis[v] * featb[c_e]  (F = 128) --
// 4 waves/block, one node per wave. Lanes 0-31 edge j, lanes 32-63 edge j+1;
// each lane covers 4 channels (8 B load). Cross-half reduce via shfl_xor(32).

template<bool BIAS, bool RELU>
__global__ __launch_bounds__(256)
void k_agg_bf(const unsigned short* __restrict__ featb, const int* __restrict__ col,
              const int* __restrict__ off, const int* __restrict__ len,
              const float* __restrict__ dis, const float* __restrict__ bias,
              float* __restrict__ out) {
    int wid  = threadIdx.x >> 6;
    int lane = threadIdx.x & 63;
    int v = blockIdx.x * 4 + wid;          // grid is exactly N_NODES/4
    int start = off[v];
    int lenv  = len[v];
    float disv = dis[v];
    int half = lane >> 5;                  // which edge of the pair
    int q    = lane & 31;                  // channel quad: ch q*4..q*4+3
    float4 acc = make_float4(0.f, 0.f, 0.f, 0.f);
    for (int base = 0; base < lenv; base += 64) {
        int n = min(64, lenv - base);
        int   cv = 0;
        float wv = 0.f;
        if (lane < n) {
            cv = col[start + base + lane];
            wv = dis[cv] * disv;
        }
        auto pair = [&](int j) {
            int   c = __shfl(cv, j + half);   // j+half==n on odd tail -> w=0, c=0
            float w = __shfl(wv, j + half);
            uint2 d = *(const uint2*)&featb[(size_t)c * 128 + q * 4];
            acc.x = fmaf(w, __uint_as_float(d.x << 16),         acc.x);
            acc.y = fmaf(w, __uint_as_float(d.x & 0xffff0000u), acc.y);
            acc.z = fmaf(w, __uint_as_float(d.y << 16),         acc.z);
            acc.w = fmaf(w, __uint_as_float(d.y & 0xffff0000u), acc.w);
        };
        int j = 0;
        for (; j + 8 <= n; j += 8) { pair(j); pair(j + 2); pair(j + 4); pair(j + 6); }
        for (; j < n; j += 2) pair(j);
    }
    acc.x += __shfl_xor(acc.x, 32);
    acc.y += __shfl_xor(acc.y, 32);
    acc.z += __shfl_xor(acc.z, 32);
    acc.w += __shfl_xor(acc.w, 32);
    if (half == 0) {
        float4 o = acc;
        if (BIAS) {
            float4 b = *(const float4*)&bias[q * 4];
            o.x += b.x; o.y += b.y; o.z += b.z; o.w += b.w;
        }
        if (RELU) {
            o.x = fmaxf(o.x, 0.f); o.y = fmaxf(o.y, 0.f);
            o.z = fmaxf(o.z, 0.f); o.w = fmaxf(o.w, 0.f);
        }
        *(float4*)&out[(size_t)v * 128 + q * 4] = o;
    }
}

// ---- W split into MFMA-fragment-ordered bf16 hi/lo --------------------------
// Fragment layout (16x16x32 bf16): B col n = lane&15, k = (lane>>4)*8 + i.

template<int K, int NC>
__global__ void k_wsplit(const float* __restrict__ W, u32x4* __restrict__ Wf) {
    constexpr int KT = K / 32, NT = NC / 16;
    int tid = blockIdx.x * blockDim.x + threadIdx.x;
    if (tid >= KT * NT * 64) return;
    int lane = tid & 63;
    int ntk  = tid >> 6;           // kt*NT + nt
    int kt = ntk / NT, nt = ntk % NT;
    int kb = kt * 32 + (lane >> 4) * 8;
    int n  = nt * 16 + (lane & 15);
    unsigned int hh[4], ll[4];
    #pragma unroll
    for (int j = 0; j < 4; ++j) {
        float x0 = W[(size_t)(kb + 2 * j) * NC + n];
        float x1 = W[(size_t)(kb + 2 * j + 1) * NC + n];
        split2(x0, x1, hh[j], ll[j]);
    }
    Wf[(size_t)(ntk * 2 + 0) * 64 + lane] = (u32x4){hh[0], hh[1], hh[2], hh[3]};
    Wf[(size_t)(ntk * 2 + 1) * 64 + lane] = (u32x4){ll[0], ll[1], ll[2], ll[3]};
}

// ---- MFMA GEMM: out[M,NC] = A[M,K] @ W[K,NC] (+bias, relu), split-bf16 3-pass ----

template<int K, int NC, bool BIAS, bool RELU, bool BF16OUT>
__global__ __launch_bounds__(128)
void k_gemm_mfma(const float* __restrict__ A, const u32x4* __restrict__ Wf,
                 const float* __restrict__ bias, void* __restrict__ outv, int M) {
    constexpr int KT = K / 32, NT = NC / 16, NTW = NT / 2;
    int lane = threadIdx.x & 63;
    int wid  = threadIdx.x >> 6;
    int lq = lane >> 4;            // 0..3
    int lr = lane & 15;
    int kq = lq * 8;
    int rbase = blockIdx.x * 32;
    int nt0 = wid * NTW;

    f32x4 acc[2][NTW];
    #pragma unroll
    for (int s = 0; s < 2; ++s)
        #pragma unroll
        for (int t = 0; t < NTW; ++t)
            acc[s][t] = (f32x4){0.f, 0.f, 0.f, 0.f};

    for (int kt = 0; kt < KT; ++kt) {
        bf16x8 ah[2], al[2];
        #pragma unroll
        for (int s = 0; s < 2; ++s) {
            int row = rbase + s * 16 + lr;
            const float* Ar = A + (size_t)min(row, M - 1) * K + kt * 32 + kq;
            float4 u = *(const float4*)Ar;
            float4 v = *(const float4*)(Ar + 4);
            unsigned int h0, l0, h1, l1, h2, l2, h3, l3;
            split2(u.x, u.y, h0, l0); split2(u.z, u.w, h1, l1);
            split2(v.x, v.y, h2, l2); split2(v.z, v.w, h3, l3);
            ah[s] = asbf((u32x4){h0, h1, h2, h3});
            al[s] = asbf((u32x4){l0, l1, l2, l3});
        }
        #pragma unroll
        for (int t = 0; t < NTW; ++t) {
            int nt = nt0 + t;
            const u32x4* wp = Wf + (size_t)((kt * NT + nt) * 2) * 64 + lane;
            bf16x8 bh = asbf(wp[0]);
            bf16x8 bl = asbf(wp[64]);
            // D = Ah*Wh + Al*Wh + Ah*Wl  (drop Al*Wl ~ 2^-18)
            acc[0][t] = __builtin_amdgcn_mfma_f32_16x16x32_bf16(ah[0], bh, acc[0][t], 0, 0, 0);
            acc[1][t] = __builtin_amdgcn_mfma_f32_16x16x32_bf16(ah[1], bh, acc[1][t], 0, 0, 0);
            acc[0][t] = __builtin_amdgcn_mfma_f32_16x16x32_bf16(al[0], bh, acc[0][t], 0, 0, 0);
            acc[1][t] = __builtin_amdgcn_mfma_f32_16x16x32_bf16(al[1], bh, acc[1][t], 0, 0, 0);
            acc[0][t] = __builtin_amdgcn_mfma_f32_16x16x32_bf16(ah[0], bl, acc[0][t], 0, 0, 0);
            acc[1][t] = __builtin_amdgcn_mfma_f32_16x16x32_bf16(ah[1], bl, acc[1][t], 0, 0, 0);
        }
    }

    // epilogue: D col = lane&15, row = (lane>>4)*4 + j
    #pragma unroll
    for (int t = 0; t < NTW; ++t) {
        int colg = (nt0 + t) * 16 + lr;
        float bv = BIAS ? bias[colg] : 0.f;
        #pragma unroll
        for (int s = 0; s < 2; ++s) {
            #pragma unroll
            for (int j = 0; j < 4; ++j) {
                int row = rbase + s * 16 + lq * 4 + j;
                if (row < M) {
                    float o = acc[s][t][j] + bv;
                    if (RELU) o = fmaxf(o, 0.f);
                    if (BF16OUT)
                        ((unsigned short*)outv)[(size_t)row * NC + colg] = (unsigned short)bf16rn(o);
                    else
                        ((float*)outv)[(size_t)row * NC + colg] = o;
                }
            }
        }
    }
}

// ---------------- launch ----------------

extern "C" void kernel_launch(void* const* d_in, const int* in_sizes, int n_in,
                              void* d_out, int out_size, void* d_ws, size_t ws_size,
                              hipStream_t stream) {
    const float* x   = (const float*)d_in[0];
    const int*   ei  = (const int*)d_in[1];
    const int*   src = ei;
    const int*   dst = ei + N_EDGES;
    const float* W1  = (const float*)d_in[3];
    const float* b1  = (const float*)d_in[4];
    const float* W2  = (const float*)d_in[5];
    const float* b2  = (const float*)d_in[6];
    float* out = (float*)d_out;

    char* ws = (char*)d_ws;
    size_t o = 0;
    auto carve = [&](size_t bytes) {
        void* p = ws + o;
        o += (bytes + 255) & ~(size_t)255;
        return p;
    };
    int*   deg9   = (int*)  carve((size_t)TOT9 * 4);
    int*   cur9   = (int*)  carve((size_t)TOT9 * 4);
    int*   incl9  = (int*)  carve((size_t)TOT9 * 4);   // becomes off9 in place
    int*   part9  = (int*)  carve(SCAN_BLK * 4);
    int*   off    = (int*)  carve(N_NODES * 4);
    int*   len    = (int*)  carve(N_NODES * 4);
    float* dis    = (float*)carve(N_NODES * 4);
    int*   col    = (int*)  carve((size_t)TOTAL_E * 4);
    float* agg1   = (float*)carve((size_t)N_NODES * 128 * 4);
    float* h1     = (float*)carve((size_t)N_NODES * 256 * 4);
    u32x4* Wf1    = (u32x4*)carve((size_t)(IN_CH/32) * (HID_CH/16) * 2 * 64 * 16);
    u32x4* Wf2    = (u32x4*)carve((size_t)(HID_CH/32) * (OUT_CH/16) * 2 * 64 * 16);
    int*   off9   = incl9;                 // in-place exclusive scan
    // Aliases (lifetimes by launch order):
    //   xb  aliases h1  : xb written first, dead after agg1; h1 written in gemm1
    //   t2b aliases agg1: agg1 dead after gemm1; t2b written by gemm2, read by agg2
    unsigned short* xb  = (unsigned short*)h1;
    unsigned short* t2b = (unsigned short*)agg1;

    const int B = 256;
    k_tobf    <<<(N_NODES * 128 / 8 + B - 1) / B, B, 0, stream>>>(x, xb, N_NODES * 128 / 8);
    k_init9   <<<(TOT9 + B - 1) / B, B, 0, stream>>>(deg9, cur9);
    k_hist9   <<<(N_EDGES + B - 1) / B, B, 0, stream>>>(dst, deg9);
    k_scan1   <<<NB9, SCAN_BLK, 0, stream>>>(deg9, incl9, part9, TOT9);
    k_scan2   <<<1, SCAN_BLK, 0, stream>>>(part9);
    k_off9    <<<(TOT9 + B - 1) / B, B, 0, stream>>>(incl9, deg9, part9);
    k_post    <<<(N_NODES + B - 1) / B, B, 0, stream>>>(off9, off, len, dis);
    k_fill9   <<<FILL_BLOCKS, 256, 0, stream>>>(src, dst, off9, cur9, col);
    k_fillself<<<(N_NODES + B - 1) / B, B, 0, stream>>>(off9, col);

    k_wsplit<IN_CH,  HID_CH><<<( (IN_CH/32)*(HID_CH/16)*64 + B - 1) / B, B, 0, stream>>>(W1, Wf1);
    k_wsplit<HID_CH, OUT_CH><<<( (HID_CH/32)*(OUT_CH/16)*64 + B - 1) / B, B, 0, stream>>>(W2, Wf2);

    // layer 1: agg1 = A xb ; h1 = relu(agg1 @ W1 + b1)   (clobbers xb, now dead)
    k_agg_bf<false, false><<<N_NODES / 4, 256, 0, stream>>>(xb, col, off, len, dis, nullptr, agg1);
    k_gemm_mfma<IN_CH, HID_CH, true, true, false>
        <<<(N_NODES + 31) / 32, 128, 0, stream>>>(agg1, Wf1, b1, h1, N_NODES);

    // layer 2: t2b = bf16(h1 @ W2) ; out = relu(A t2b + b2)
    k_gemm_mfma<HID_CH, OUT_CH, false, false, true>
        <<<(N_NODES + 31) / 32, 128, 0, stream>>>(h1, Wf2, nullptr, t2b, N_NODES);
    k_agg_bf<true, true><<<N_NODES / 4, 256, 0, stream>>>(t2b, col, off, len, dis, b2, out);
}